// Round 4
// baseline (189.548 us; speedup 1.0000x reference)
//
#include <hip/hip_runtime.h>
#include <hip/hip_bf16.h>

// GAT on MI355X. Inputs fp32 (+ int32 adj); output fp32 [8 | 4096*8].
//  kA0: W -> Wt bf16 (B-layout); WhT rows 8..15 init (col8=ones); mhat/out init
//  kA : Wh = x @ W via MFMA (16 waves, K split 16x256); x deep-prefetched (16 loads
//       in flight) -> HBM-BW-bound. Epilogue: WhT bf16, scores, atomicMax mhat.
//  kD : MFMA attention, 4 heads/wave, full software pipeline: adj+WhT double-
//       buffered in regs, sdst hoisted; epilogue head-mean -> neF + fused
//       log_softmax + w_lin reduce -> atomicAdd out
typedef __attribute__((ext_vector_type(8))) short bf16x8;
typedef __attribute__((ext_vector_type(4))) float f32x4;

#define NN 4096
#define NC 8

__device__ __forceinline__ short f2bf(float f) {
  __hip_bfloat16 h = __float2bfloat16(f);
  return *reinterpret_cast<short*>(&h);
}
__device__ __forceinline__ unsigned fenc(float v) {
  int b = __float_as_int(v);
  return (b >= 0) ? ((unsigned)b | 0x80000000u) : (unsigned)(~b);
}
__device__ __forceinline__ float fdec(unsigned k) {
  int b = (k & 0x80000000u) ? (int)(k & 0x7FFFFFFFu) : ~(int)k;
  return __int_as_float(b);
}
__device__ __forceinline__ bool is_adj(const void* p) {
  const unsigned* u = (const unsigned*)p;
  unsigned m = u[0] | u[1] | u[2] | u[3] | u[100] | u[1000];
  return m <= 1u;
}

// ---------- kA0 ----------
__global__ __launch_bounds__(256) void kA0(const float* __restrict__ W, short* __restrict__ Wt,
                                           short* __restrict__ WhT, const float* __restrict__ blin,
                                           float* __restrict__ outF, unsigned* __restrict__ mhatU) {
  int t = threadIdx.x;
  int idx = blockIdx.x * 256 + t;            // 131072
  int h = idx >> 15, r = idx & 32767, f = r >> 3, o = r & 7;
  Wt[(size_t)(h * 8 + o) * NN + f] = f2bf(W[idx]);
  int n2 = 8 + (r >> 12);
  int j2 = r & 4095;
  WhT[((size_t)(h * 16 + n2)) * NN + j2] = (n2 == 8) ? (short)0x3F80 : (short)0;
  if (blockIdx.x == 0) {
    if (t < 4) mhatU[t] = 0u;
    if (t >= 8 && t < 16) outF[t - 8] = blin[0];
  }
}

// ---------- kA: 256 blocks x 1024 thr (16 waves). wave w: k in [w*256,(w+1)*256) ----------
__global__ __launch_bounds__(1024) void kA(const void* __restrict__ c0, const void* __restrict__ c1,
                                           const short* __restrict__ Wt,
                                           short* __restrict__ WhT, float* __restrict__ ssrc,
                                           float* __restrict__ sdst, const float* __restrict__ a,
                                           unsigned* __restrict__ mhatU) {
  const float* x = (const float*)(is_adj(c0) ? c1 : c0);
  int m0 = blockIdx.x * 16;
  int t = threadIdx.x;
  int w = t >> 6, lane = t & 63;
  int mr = lane & 15, q = lane >> 4;
  const f32x4*  ap  = (const f32x4*)(x + (size_t)(m0 + mr) * NN + w * 256 + q * 8);
  const bf16x8* b0p = (const bf16x8*)(Wt + (size_t)mr        * NN + w * 256 + q * 8);
  const bf16x8* b1p = (const bf16x8*)(Wt + (size_t)(16 + mr) * NN + w * 256 + q * 8);
  // deep prefetch: all 16 x-loads in flight before first use
  f32x4 xs[16];
#pragma unroll
  for (int kk = 0; kk < 8; ++kk) {
    xs[2 * kk]     = ap[kk * 8];
    xs[2 * kk + 1] = ap[kk * 8 + 1];
  }
  f32x4 acc0 = {0.f, 0.f, 0.f, 0.f}, acc1 = {0.f, 0.f, 0.f, 0.f};
#pragma unroll
  for (int kk = 0; kk < 8; ++kk) {
    bf16x8 b0 = b0p[kk * 4];
    bf16x8 b1 = b1p[kk * 4];
    bf16x8 af;
#pragma unroll
    for (int e = 0; e < 4; ++e) {
      af[e]     = f2bf(xs[2 * kk][e]);
      af[4 + e] = f2bf(xs[2 * kk + 1][e]);
    }
    acc0 = __builtin_amdgcn_mfma_f32_16x16x32_bf16(af, b0, acc0, 0, 0, 0);
    acc1 = __builtin_amdgcn_mfma_f32_16x16x32_bf16(af, b1, acc1, 0, 0, 0);
  }
  __shared__ float red[16][16][32];
  __shared__ float whole[16][32];
#pragma unroll
  for (int r = 0; r < 4; ++r) {
    red[w][q * 4 + r][mr]      = acc0[r];
    red[w][q * 4 + r][16 + mr] = acc1[r];
  }
  __syncthreads();
  if (t < 512) {
    int m = t >> 5, c = t & 31;
    float s = 0.f;
#pragma unroll
    for (int ww = 0; ww < 16; ++ww) s += red[ww][m][c];
    whole[m][c] = s;
    int h = c >> 3, o = c & 7;
    WhT[((size_t)(h * 16 + o)) * NN + (m0 + m)] = f2bf(s);
  }
  __syncthreads();
  if (t < 64) {
    int h = t >> 4, m = t & 15;
    float s1 = 0.f, s2 = 0.f;
#pragma unroll
    for (int o = 0; o < 8; ++o) {
      float v = whole[m][h * 8 + o];
      s1 += v * a[h * 16 + o];
      s2 += v * a[h * 16 + 8 + o];
    }
    ssrc[h * NN + m0 + m] = s1;
    sdst[h * NN + m0 + m] = s2;
    float mx = s2;
#pragma unroll
    for (int mm = 1; mm <= 8; mm <<= 1) mx = fmaxf(mx, __shfl_xor(mx, mm));
    if ((t & 15) == 0) atomicMax(&mhatU[h], fenc(mx));
  }
}

// ---------- kD: 256 blocks x 1024 thr (16 waves). wave w -> j in [w*256,(w+1)*256), 4 heads ----------
// Fully unrolled 8-chunk j-loop; adj + WhT double-buffered in registers (slot = c&1),
// sdst hoisted to chunk top. All array indices compile-time constant (no scratch).
__global__ __launch_bounds__(1024) void kD(const void* __restrict__ c0, const void* __restrict__ c1,
                                           const short* __restrict__ WhT,
                                           const float* __restrict__ ssrcg, const float* __restrict__ sdstg,
                                           const unsigned* __restrict__ mhatU,
                                           const float* __restrict__ wlin,
                                           float* __restrict__ outF, float* __restrict__ neF) {
  const int* adj = (const int*)(is_adj(c0) ? c0 : c1);
  __shared__ float red[16][4][16][10];     // 40 KB
  __shared__ float ps[2][8];
  int t = threadIdx.x;
  int w = t >> 6, lane = t & 63;
  int n = lane & 15, q = lane >> 4;
  int i0 = blockIdx.x * 16;
  int j0 = w * 256;
  const float L2E = 1.4426950408889634f;
  float mh0 = fdec(mhatU[0]) * L2E, mh1 = fdec(mhatU[1]) * L2E;
  float mh2 = fdec(mhatU[2]) * L2E, mh3 = fdec(mhatU[3]) * L2E;
  float ssr0 = ssrcg[0 * NN + i0 + n] * L2E;
  float ssr1 = ssrcg[1 * NN + i0 + n] * L2E;
  float ssr2 = ssrcg[2 * NN + i0 + n] * L2E;
  float ssr3 = ssrcg[3 * NN + i0 + n] * L2E;
  float tb0 = ssr0 + mh0, tb1 = ssr1 + mh1, tb2 = ssr2 + mh2, tb3 = ssr3 + mh3;
  float eb0 = fmaxf(tb0, 0.2f * tb0), eb1 = fmaxf(tb1, 0.2f * tb1);
  float eb2 = fmaxf(tb2, 0.2f * tb2), eb3 = fmaxf(tb3, 0.2f * tb3);
  const int4*   adjp4 = (const int4*)(adj + (size_t)(i0 + n) * NN + j0) + q * 2;
  const f32x4*  sp0 = (const f32x4*)(sdstg + 0 * NN + j0 + q * 8);
  const f32x4*  sp1 = (const f32x4*)(sdstg + 1 * NN + j0 + q * 8);
  const f32x4*  sp2 = (const f32x4*)(sdstg + 2 * NN + j0 + q * 8);
  const f32x4*  sp3 = (const f32x4*)(sdstg + 3 * NN + j0 + q * 8);
  const bf16x8* bp0 = (const bf16x8*)(WhT + (size_t)(0 * 16 + n) * NN + j0 + q * 8);
  const bf16x8* bp1 = (const bf16x8*)(WhT + (size_t)(1 * 16 + n) * NN + j0 + q * 8);
  const bf16x8* bp2 = (const bf16x8*)(WhT + (size_t)(2 * 16 + n) * NN + j0 + q * 8);
  const bf16x8* bp3 = (const bf16x8*)(WhT + (size_t)(3 * 16 + n) * NN + j0 + q * 8);
  f32x4 acc0 = {0.f,0.f,0.f,0.f}, acc1 = {0.f,0.f,0.f,0.f};
  f32x4 acc2 = {0.f,0.f,0.f,0.f}, acc3 = {0.f,0.f,0.f,0.f};
  int4   pa0[2], pa1[2];
  bf16x8 pb0[2], pb1[2], pb2[2], pb3[2];

#define LOADK(s, c)                                                      \
  { pa0[s] = adjp4[(c) * 8]; pa1[s] = adjp4[(c) * 8 + 1];                \
    pb0[s] = bp0[(c) * 4];   pb1[s] = bp1[(c) * 4];                      \
    pb2[s] = bp2[(c) * 4];   pb3[s] = bp3[(c) * 4]; }

#define HSTEP(H, s, SA0, SA1, ACC)                                       \
  { bf16x8 af;                                                           \
    _Pragma("unroll")                                                    \
    for (int e = 0; e < 4; ++e) {                                        \
      float tt = fmaf(SA0[e], L2E, ssr##H);                              \
      float ee = fmaxf(tt, 0.2f * tt);                                   \
      float wv = __builtin_amdgcn_exp2f(ee - eb##H);                     \
      af[e] = f2bf(mk[e] ? wv : 0.f);                                    \
    }                                                                    \
    _Pragma("unroll")                                                    \
    for (int e = 0; e < 4; ++e) {                                        \
      float tt = fmaf(SA1[e], L2E, ssr##H);                              \
      float ee = fmaxf(tt, 0.2f * tt);                                   \
      float wv = __builtin_amdgcn_exp2f(ee - eb##H);                     \
      af[4 + e] = f2bf(mk[4 + e] ? wv : 0.f);                            \
    }                                                                    \
    ACC = __builtin_amdgcn_mfma_f32_16x16x32_bf16(af, pb##H[s], ACC, 0, 0, 0); }

  LOADK(0, 0)
#pragma unroll
  for (int c = 0; c < 8; ++c) {
    int cur = c & 1, nxt = cur ^ 1;
    if (c < 7) { LOADK(nxt, c + 1) }
    // hoist all sdst loads for this chunk (one waitcnt staircase)
    f32x4 sA0 = sp0[c * 8], sA1 = sp0[c * 8 + 1];
    f32x4 sB0 = sp1[c * 8], sB1 = sp1[c * 8 + 1];
    f32x4 sC0 = sp2[c * 8], sC1 = sp2[c * 8 + 1];
    f32x4 sD0 = sp3[c * 8], sD1 = sp3[c * 8 + 1];
    int avs[8] = {pa0[cur].x, pa0[cur].y, pa0[cur].z, pa0[cur].w,
                  pa1[cur].x, pa1[cur].y, pa1[cur].z, pa1[cur].w};
    bool mk[8];
#pragma unroll
    for (int e = 0; e < 8; ++e) mk[e] = avs[e] > 0;
    HSTEP(0, cur, sA0, sA1, acc0)
    HSTEP(1, cur, sB0, sB1, acc1)
    HSTEP(2, cur, sC0, sC1, acc2)
    HSTEP(3, cur, sD0, sD1, acc3)
  }
#undef LOADK
#undef HSTEP

  if (n < 9) {
#pragma unroll
    for (int r = 0; r < 4; ++r) {
      red[w][0][q * 4 + r][n] = acc0[r];
      red[w][1][q * 4 + r][n] = acc1[r];
      red[w][2][q * 4 + r][n] = acc2[r];
      red[w][3][q * 4 + r][n] = acc3[r];
    }
  }
  __syncthreads();
  if (t < 128) {
    int i = t >> 3, o = t & 7;
    float tot = 0.f;
#pragma unroll
    for (int h = 0; h < 4; ++h) {
      float s = 0.f, l = 0.f;
#pragma unroll
      for (int ww = 0; ww < 16; ++ww) {
        s += red[ww][h][i][o];
        l += red[ww][h][i][8];
      }
      tot += s / l;
    }
    float ne = 0.25f * tot;
    neF[(size_t)(i0 + i) * NC + o] = ne;
    float m = ne;
#pragma unroll
    for (int mm = 1; mm <= 4; mm <<= 1) m = fmaxf(m, __shfl_xor(m, mm));
    float ex = __expf(ne - m);
    float s8 = ex;
#pragma unroll
    for (int mm = 1; mm <= 4; mm <<= 1) s8 += __shfl_xor(s8, mm);
    float ln = m + __logf(s8);
    float p = (ne - ln) * wlin[i0 + i];
#pragma unroll
    for (int mm = 8; mm <= 32; mm <<= 1) p += __shfl_xor(p, mm);
    if ((t & 63) < 8) ps[t >> 6][t & 7] = p;
  }
  __syncthreads();
  if (t < 8) atomicAdd(&outF[t], ps[0][t] + ps[1][t]);
}

extern "C" void kernel_launch(void* const* d_in, const int* in_sizes, int n_in,
                              void* d_out, int out_size, void* d_ws, size_t ws_size,
                              hipStream_t stream) {
  const void* big0 = nullptr; const void* big1 = nullptr;
  const float* W = nullptr; const float* a = nullptr;
  const float* wlin = nullptr; const float* blin = nullptr;
  for (int idx = 0; idx < n_in; ++idx) {
    int sz = in_sizes[idx];
    if (sz == NN * NN)          { if (!big0) big0 = d_in[idx]; else big1 = d_in[idx]; }
    else if (sz == 4 * NN * NC) W    = (const float*)d_in[idx];
    else if (sz == 64)          a    = (const float*)d_in[idx];
    else if (sz == NN)          wlin = (const float*)d_in[idx];
    else if (sz == 1)           blin = (const float*)d_in[idx];
  }
  float* outF = (float*)d_out;       // fp32: [8] out | [4096][8] node_embeddings
  float* neF  = outF + 8;

  char* ws = (char*)d_ws;
  short*    Wt    = (short*)(ws + 0);       // 262144 B
  short*    WhT   = (short*)(ws + 262144);  // 524288 B : [4h][16][4096] bf16 (col8=1)
  float*    ssrc  = (float*)(ws + 786432);  // 65536 B
  float*    sdst  = (float*)(ws + 851968);  // 65536 B
  unsigned* mhatU = (unsigned*)(ws + 917504); // 16 B

  kA0<<<512, 256, 0, stream>>>(W, Wt, WhT, blin, outF, mhatU);
  kA <<<256, 1024, 0, stream>>>(big0, big1, Wt, WhT, ssrc, sdst, a, mhatU);
  kD <<<256, 1024, 0, stream>>>(big0, big1, WhT, ssrc, sdst, mhatU, wlin, outF, neF);
}

// Round 5
// 187.749 us; speedup vs baseline: 1.0096x; 1.0096x over previous
//
#include <hip/hip_runtime.h>
#include <hip/hip_bf16.h>

// GAT on MI355X. Inputs fp32 (+ int32 adj); output fp32 [8 | 4096*8].
//  kA0: W -> Wt bf16 (B-layout); WhT rows 8..15 init (col8=ones); mhat/out init
//  kA : Wh = x @ W via MFMA (16 waves); epilogue: WhT bf16, scores PRE-SCALED by
//       log2(e), atomicMax mhat (scaled).
//  kD : LDS-staged MFMA attention (global_load_lds async DMA, XOR-swizzled rows),
//       4 chunks/wave/tile from LDS; epilogue head-mean -> neF + fused
//       log_softmax + w_lin reduce -> atomicAdd out
typedef __attribute__((ext_vector_type(8))) short bf16x8;
typedef __attribute__((ext_vector_type(4))) float f32x4;

#define NN 4096
#define NC 8
#define L2EF 1.4426950408889634f

__device__ __forceinline__ short f2bf(float f) {
  __hip_bfloat16 h = __float2bfloat16(f);
  return *reinterpret_cast<short*>(&h);
}
__device__ __forceinline__ unsigned fenc(float v) {
  int b = __float_as_int(v);
  return (b >= 0) ? ((unsigned)b | 0x80000000u) : (unsigned)(~b);
}
__device__ __forceinline__ float fdec(unsigned k) {
  int b = (k & 0x80000000u) ? (int)(k & 0x7FFFFFFFu) : ~(int)k;
  return __int_as_float(b);
}
__device__ __forceinline__ bool is_adj(const void* p) {
  const unsigned* u = (const unsigned*)p;
  unsigned m = u[0] | u[1] | u[2] | u[3] | u[100] | u[1000];
  return m <= 1u;
}
__device__ __forceinline__ void gll16(const void* g, void* l) {
  __builtin_amdgcn_global_load_lds((const __attribute__((address_space(1))) void*)g,
                                   (__attribute__((address_space(3))) void*)l, 16, 0, 0);
}

// ---------- kA0 ----------
__global__ __launch_bounds__(256) void kA0(const float* __restrict__ W, short* __restrict__ Wt,
                                           short* __restrict__ WhT, const float* __restrict__ blin,
                                           float* __restrict__ outF, unsigned* __restrict__ mhatU) {
  int t = threadIdx.x;
  int idx = blockIdx.x * 256 + t;            // 131072
  int h = idx >> 15, r = idx & 32767, f = r >> 3, o = r & 7;
  Wt[(size_t)(h * 8 + o) * NN + f] = f2bf(W[idx]);
  int n2 = 8 + (r >> 12);
  int j2 = r & 4095;
  WhT[((size_t)(h * 16 + n2)) * NN + j2] = (n2 == 8) ? (short)0x3F80 : (short)0;
  if (blockIdx.x == 0) {
    if (t < 4) mhatU[t] = 0u;
    if (t >= 8 && t < 16) outF[t - 8] = blin[0];
  }
}

// ---------- kA: 256 blocks x 1024 thr (16 waves). wave w: k in [w*256,(w+1)*256) ----------
__global__ __launch_bounds__(1024) void kA(const void* __restrict__ c0, const void* __restrict__ c1,
                                           const short* __restrict__ Wt,
                                           short* __restrict__ WhT, float* __restrict__ ssrc,
                                           float* __restrict__ sdst, const float* __restrict__ a,
                                           unsigned* __restrict__ mhatU) {
  const float* x = (const float*)(is_adj(c0) ? c1 : c0);
  int m0 = blockIdx.x * 16;
  int t = threadIdx.x;
  int w = t >> 6, lane = t & 63;
  int mr = lane & 15, q = lane >> 4;
  const f32x4*  ap  = (const f32x4*)(x + (size_t)(m0 + mr) * NN + w * 256 + q * 8);
  const bf16x8* b0p = (const bf16x8*)(Wt + (size_t)mr        * NN + w * 256 + q * 8);
  const bf16x8* b1p = (const bf16x8*)(Wt + (size_t)(16 + mr) * NN + w * 256 + q * 8);
  // deep prefetch: all 16 x-loads in flight before first use
  f32x4 xs[16];
#pragma unroll
  for (int kk = 0; kk < 8; ++kk) {
    xs[2 * kk]     = ap[kk * 8];
    xs[2 * kk + 1] = ap[kk * 8 + 1];
  }
  f32x4 acc0 = {0.f, 0.f, 0.f, 0.f}, acc1 = {0.f, 0.f, 0.f, 0.f};
#pragma unroll
  for (int kk = 0; kk < 8; ++kk) {
    bf16x8 b0 = b0p[kk * 4];
    bf16x8 b1 = b1p[kk * 4];
    bf16x8 af;
#pragma unroll
    for (int e = 0; e < 4; ++e) {
      af[e]     = f2bf(xs[2 * kk][e]);
      af[4 + e] = f2bf(xs[2 * kk + 1][e]);
    }
    acc0 = __builtin_amdgcn_mfma_f32_16x16x32_bf16(af, b0, acc0, 0, 0, 0);
    acc1 = __builtin_amdgcn_mfma_f32_16x16x32_bf16(af, b1, acc1, 0, 0, 0);
  }
  __shared__ float red[16][16][32];
  __shared__ float whole[16][32];
#pragma unroll
  for (int r = 0; r < 4; ++r) {
    red[w][q * 4 + r][mr]      = acc0[r];
    red[w][q * 4 + r][16 + mr] = acc1[r];
  }
  __syncthreads();
  if (t < 512) {
    int m = t >> 5, c = t & 31;
    float s = 0.f;
#pragma unroll
    for (int ww = 0; ww < 16; ++ww) s += red[ww][m][c];
    whole[m][c] = s;
    int h = c >> 3, o = c & 7;
    WhT[((size_t)(h * 16 + o)) * NN + (m0 + m)] = f2bf(s);
  }
  __syncthreads();
  if (t < 64) {
    int h = t >> 4, m = t & 15;
    float s1 = 0.f, s2 = 0.f;
#pragma unroll
    for (int o = 0; o < 8; ++o) {
      float v = whole[m][h * 8 + o];
      s1 += v * a[h * 16 + o];
      s2 += v * a[h * 16 + 8 + o];
    }
    ssrc[h * NN + m0 + m] = s1 * L2EF;     // pre-scaled by log2(e)
    sdst[h * NN + m0 + m] = s2 * L2EF;
    float mx = s2 * L2EF;
#pragma unroll
    for (int mm = 1; mm <= 8; mm <<= 1) mx = fmaxf(mx, __shfl_xor(mx, mm));
    if ((t & 15) == 0) atomicMax(&mhatU[h], fenc(mx));
  }
}

// ---------- kD: 256 blocks x 1024 thr (16 waves). LDS-staged tiles of 512 j ----------
// wave w: head h = w&3, j-quarter jq = w>>2 (128 j per wave per tile = 4 chunks of 32).
// adjS/whS rows XOR-swizzled (byte ^ ((row&7)<<4)) via pre-swizzled global source
// (rule #21: linear DMA dest + inverse-swizzled source + swizzled read). sdS is a
// 16-lane broadcast read -> no swizzle needed.
__global__ __launch_bounds__(1024) void kD(const void* __restrict__ c0, const void* __restrict__ c1,
                                           const short* __restrict__ WhT,
                                           const float* __restrict__ ssrcg, const float* __restrict__ sdstg,
                                           const unsigned* __restrict__ mhatU,
                                           const float* __restrict__ wlin,
                                           float* __restrict__ outF, float* __restrict__ neF) {
  const int* adj = (const int*)(is_adj(c0) ? c0 : c1);
  __shared__ int   adjS[16][512];     // 32 KB
  __shared__ short whS[4][16][512];   // 64 KB (rows o=8..15 = ones/zeros from kA0)
  __shared__ float sdS[4][512];       // 8 KB
  __shared__ float ps[2][8];
  int t = threadIdx.x;
  int w = t >> 6, lane = t & 63;
  int h = w & 3, jq = w >> 2;
  int m = lane & 15, q = lane >> 4;
  int i0 = blockIdx.x * 16;
  unsigned km = (unsigned)((m & 7) << 4);

  float mh  = fdec(mhatU[h]);                // pre-scaled
  float ssr = ssrcg[h * NN + i0 + m];        // pre-scaled
  float tb  = ssr + mh;
  float eb  = fmaxf(tb, 0.2f * tb);
  const char* adjRow = (const char*)&adjS[m][0];
  const char* whRow  = (const char*)&whS[h][m][0];
  const char* sdRow  = (const char*)&sdS[h][0];
  // staging assignment
  int rs = w >> 1, half = w & 1;
  unsigned keyA = (unsigned)((rs & 7) << 4);
  unsigned keyW = (unsigned)((w & 7) << 4);
  f32x4 acc = {0.f, 0.f, 0.f, 0.f};

  for (int jt = 0; jt < 8; ++jt) {
    __syncthreads();                          // previous tile's compute done
    {
      const char* ga0 = (const char*)(adj + (size_t)(i0 + rs) * NN + jt * 512 + half * 256) + ((lane * 16) ^ keyA);
      gll16(ga0, &adjS[rs][half * 256]);
      const char* ga1 = (const char*)(adj + (size_t)(i0 + 8 + rs) * NN + jt * 512 + half * 256) + ((lane * 16) ^ keyA);
      gll16(ga1, &adjS[8 + rs][half * 256]);
#pragma unroll
      for (int i = 0; i < 4; ++i) {
        const char* gw = (const char*)(WhT + (size_t)(i * 16 + w) * NN + jt * 512) + ((lane * 16) ^ keyW);
        gll16(gw, &whS[i][w][0]);
      }
      if (w < 8) {
        const char* gs = (const char*)(sdstg + (size_t)(w >> 1) * NN + jt * 512 + (w & 1) * 256) + lane * 16;
        gll16(gs, &sdS[w >> 1][(w & 1) * 256]);
      }
    }
    __syncthreads();                          // drains vmcnt -> LDS valid
#pragma unroll
    for (int c = 0; c < 4; ++c) {
      int jb = jq * 512 + c * 128 + q * 32;   // byte offset in 2048-B rows
      int4  a0 = *(const int4*)(adjRow + ((jb)      ^ km));
      int4  a1 = *(const int4*)(adjRow + ((jb + 16) ^ km));
      f32x4 s0 = *(const f32x4*)(sdRow + jb);
      f32x4 s1 = *(const f32x4*)(sdRow + jb + 16);
      int jw = jq * 256 + c * 64 + q * 16;    // byte offset in 1024-B rows
      bf16x8 bv = *(const bf16x8*)(whRow + (jw ^ km));
      int   avs[8] = {a0.x, a0.y, a0.z, a0.w, a1.x, a1.y, a1.z, a1.w};
      float sdv[8] = {s0[0], s0[1], s0[2], s0[3], s1[0], s1[1], s1[2], s1[3]};
      bf16x8 af;
#pragma unroll
      for (int e = 0; e < 8; ++e) {
        float tt = ssr + sdv[e];
        float ee = fmaxf(tt, 0.2f * tt);
        float wv = __builtin_amdgcn_exp2f(ee - eb);
        af[e] = f2bf(avs[e] > 0 ? wv : 0.f);
      }
      acc = __builtin_amdgcn_mfma_f32_16x16x32_bf16(af, bv, acc, 0, 0, 0);
    }
  }
  __syncthreads();                            // whS dead -> alias red over it
  float* red = (float*)&whS[0][0][0];         // [16 waves][16 i][10]
  if (m < 9) {
#pragma unroll
    for (int r = 0; r < 4; ++r) red[(w * 16 + q * 4 + r) * 10 + m] = acc[r];
  }
  __syncthreads();
  if (t < 128) {
    int i = t >> 3, o = t & 7;
    float tot = 0.f;
#pragma unroll
    for (int hh = 0; hh < 4; ++hh) {
      float s = 0.f, l = 0.f;
#pragma unroll
      for (int jj = 0; jj < 4; ++jj) {
        int w2 = jj * 4 + hh;
        s += red[(w2 * 16 + i) * 10 + o];
        l += red[(w2 * 16 + i) * 10 + 8];
      }
      tot += s / l;
    }
    float ne = 0.25f * tot;
    neF[(size_t)(i0 + i) * NC + o] = ne;
    float mx = ne;
#pragma unroll
    for (int mm = 1; mm <= 4; mm <<= 1) mx = fmaxf(mx, __shfl_xor(mx, mm));
    float ex = __expf(ne - mx);
    float s8 = ex;
#pragma unroll
    for (int mm = 1; mm <= 4; mm <<= 1) s8 += __shfl_xor(s8, mm);
    float ln = mx + __logf(s8);
    float p = (ne - ln) * wlin[i0 + i];
#pragma unroll
    for (int mm = 8; mm <= 32; mm <<= 1) p += __shfl_xor(p, mm);
    if ((t & 63) < 8) ps[t >> 6][t & 7] = p;
  }
  __syncthreads();
  if (t < 8) atomicAdd(&outF[t], ps[0][t] + ps[1][t]);
}

extern "C" void kernel_launch(void* const* d_in, const int* in_sizes, int n_in,
                              void* d_out, int out_size, void* d_ws, size_t ws_size,
                              hipStream_t stream) {
  const void* big0 = nullptr; const void* big1 = nullptr;
  const float* W = nullptr; const float* a = nullptr;
  const float* wlin = nullptr; const float* blin = nullptr;
  for (int idx = 0; idx < n_in; ++idx) {
    int sz = in_sizes[idx];
    if (sz == NN * NN)          { if (!big0) big0 = d_in[idx]; else big1 = d_in[idx]; }
    else if (sz == 4 * NN * NC) W    = (const float*)d_in[idx];
    else if (sz == 64)          a    = (const float*)d_in[idx];
    else if (sz == NN)          wlin = (const float*)d_in[idx];
    else if (sz == 1)           blin = (const float*)d_in[idx];
  }
  float* outF = (float*)d_out;       // fp32: [8] out | [4096][8] node_embeddings
  float* neF  = outF + 8;

  char* ws = (char*)d_ws;
  short*    Wt    = (short*)(ws + 0);       // 262144 B
  short*    WhT   = (short*)(ws + 262144);  // 524288 B : [4h][16][4096] bf16 (col8=1)
  float*    ssrc  = (float*)(ws + 786432);  // 65536 B (pre-scaled by log2 e)
  float*    sdst  = (float*)(ws + 851968);  // 65536 B (pre-scaled by log2 e)
  unsigned* mhatU = (unsigned*)(ws + 917504); // 16 B

  kA0<<<512, 256, 0, stream>>>(W, Wt, WhT, blin, outF, mhatU);
  kA <<<256, 1024, 0, stream>>>(big0, big1, Wt, WhT, ssrc, sdst, a, mhatU);
  kD <<<256, 1024, 0, stream>>>(big0, big1, WhT, ssrc, sdst, mhatU, wlin, outF, neF);
}

// Round 6
// 186.605 us; speedup vs baseline: 1.0158x; 1.0061x over previous
//
#include <hip/hip_runtime.h>
#include <hip/hip_bf16.h>

// GAT on MI355X. Inputs fp32 (+ int32 adj); output fp32 [8 | 4096*8].
//  kA0: W -> Wt bf16; WhT rows 8..15 init (col8=ones); adj -> 1-bit mask (2 MB);
//       mhat/out init. grid 2048x256.
//  kA : Wh = x @ W via MFMA (16 waves); epilogue: WhT bf16, scores pre-scaled by
//       log2(e), atomicMax mhat.
//  kD : MFMA attention, double-buffered 256-j LDS tiles, counted vmcnt(3) + raw
//       s_barrier (loads in flight across barriers), adj from bitmask (LDS b32
//       broadcast). Epilogue: head-mean -> neF + fused log_softmax + w_lin
//       -> atomicAdd out.
typedef __attribute__((ext_vector_type(8))) short bf16x8;
typedef __attribute__((ext_vector_type(4))) float f32x4;

#define NN 4096
#define NC 8
#define L2EF 1.4426950408889634f

__device__ __forceinline__ short f2bf(float f) {
  __hip_bfloat16 h = __float2bfloat16(f);
  return *reinterpret_cast<short*>(&h);
}
__device__ __forceinline__ unsigned fenc(float v) {
  int b = __float_as_int(v);
  return (b >= 0) ? ((unsigned)b | 0x80000000u) : (unsigned)(~b);
}
__device__ __forceinline__ float fdec(unsigned k) {
  int b = (k & 0x80000000u) ? (int)(k & 0x7FFFFFFFu) : ~(int)k;
  return __int_as_float(b);
}
__device__ __forceinline__ bool is_adj(const void* p) {
  const unsigned* u = (const unsigned*)p;
  unsigned m = u[0] | u[1] | u[2] | u[3] | u[100] | u[1000];
  return m <= 1u;
}
__device__ __forceinline__ void gll16(const void* g, void* l) {
  __builtin_amdgcn_global_load_lds((const __attribute__((address_space(1))) void*)g,
                                   (__attribute__((address_space(3))) void*)l, 16, 0, 0);
}
__device__ __forceinline__ void gll4(const void* g, void* l) {
  __builtin_amdgcn_global_load_lds((const __attribute__((address_space(1))) void*)g,
                                   (__attribute__((address_space(3))) void*)l, 4, 0, 0);
}

// ---------- kA0: Wt transform + WhT init + adj bitmask pack + inits ----------
// grid 2048 x 256 = 524288 threads; thread u packs mask word u (32 adj ints).
__global__ __launch_bounds__(256) void kA0(const float* __restrict__ W, short* __restrict__ Wt,
                                           short* __restrict__ WhT, const float* __restrict__ blin,
                                           float* __restrict__ outF, unsigned* __restrict__ mhatU,
                                           const void* __restrict__ c0, const void* __restrict__ c1,
                                           unsigned* __restrict__ maskW) {
  const int* adj = (const int*)(is_adj(c0) ? c0 : c1);
  int t = threadIdx.x;
  int u = blockIdx.x * 256 + t;              // 524288
  if (u < 131072) {
    int h = u >> 15, r = u & 32767, f = r >> 3, o = r & 7;
    Wt[(size_t)(h * 8 + o) * NN + f] = f2bf(W[u]);
    int n2 = 8 + (r >> 12), j2 = r & 4095;
    WhT[((size_t)(h * 16 + n2)) * NN + j2] = (n2 == 8) ? (short)0x3F80 : (short)0;
  }
  {
    const int4* p = (const int4*)(adj + ((size_t)u << 5));   // u*32 ints, linear
    unsigned bits = 0u;
#pragma unroll
    for (int i = 0; i < 8; ++i) {
      int4 v = p[i];
      bits |= (v.x > 0 ? 1u : 0u) << (4 * i);
      bits |= (v.y > 0 ? 1u : 0u) << (4 * i + 1);
      bits |= (v.z > 0 ? 1u : 0u) << (4 * i + 2);
      bits |= (v.w > 0 ? 1u : 0u) << (4 * i + 3);
    }
    maskW[u] = bits;                          // word u: row u>>7, bits j = (u&127)*32+e
  }
  if (u < 4) mhatU[u] = 0u;
  if (u >= 8 && u < 16) outF[u - 8] = blin[0];
}

// ---------- kA: 256 blocks x 1024 thr (16 waves). wave w: k in [w*256,(w+1)*256) ----------
__global__ __launch_bounds__(1024) void kA(const void* __restrict__ c0, const void* __restrict__ c1,
                                           const short* __restrict__ Wt,
                                           short* __restrict__ WhT, float* __restrict__ ssrc,
                                           float* __restrict__ sdst, const float* __restrict__ a,
                                           unsigned* __restrict__ mhatU) {
  const float* x = (const float*)(is_adj(c0) ? c1 : c0);
  int m0 = blockIdx.x * 16;
  int t = threadIdx.x;
  int w = t >> 6, lane = t & 63;
  int mr = lane & 15, q = lane >> 4;
  const f32x4*  ap  = (const f32x4*)(x + (size_t)(m0 + mr) * NN + w * 256 + q * 8);
  const bf16x8* b0p = (const bf16x8*)(Wt + (size_t)mr        * NN + w * 256 + q * 8);
  const bf16x8* b1p = (const bf16x8*)(Wt + (size_t)(16 + mr) * NN + w * 256 + q * 8);
  f32x4 xs[16];
#pragma unroll
  for (int kk = 0; kk < 8; ++kk) {
    xs[2 * kk]     = ap[kk * 8];
    xs[2 * kk + 1] = ap[kk * 8 + 1];
  }
  f32x4 acc0 = {0.f, 0.f, 0.f, 0.f}, acc1 = {0.f, 0.f, 0.f, 0.f};
#pragma unroll
  for (int kk = 0; kk < 8; ++kk) {
    bf16x8 b0 = b0p[kk * 4];
    bf16x8 b1 = b1p[kk * 4];
    bf16x8 af;
#pragma unroll
    for (int e = 0; e < 4; ++e) {
      af[e]     = f2bf(xs[2 * kk][e]);
      af[4 + e] = f2bf(xs[2 * kk + 1][e]);
    }
    acc0 = __builtin_amdgcn_mfma_f32_16x16x32_bf16(af, b0, acc0, 0, 0, 0);
    acc1 = __builtin_amdgcn_mfma_f32_16x16x32_bf16(af, b1, acc1, 0, 0, 0);
  }
  __shared__ float red[16][16][32];
  __shared__ float whole[16][32];
#pragma unroll
  for (int r = 0; r < 4; ++r) {
    red[w][q * 4 + r][mr]      = acc0[r];
    red[w][q * 4 + r][16 + mr] = acc1[r];
  }
  __syncthreads();
  if (t < 512) {
    int m = t >> 5, c = t & 31;
    float s = 0.f;
#pragma unroll
    for (int ww = 0; ww < 16; ++ww) s += red[ww][m][c];
    whole[m][c] = s;
    int h = c >> 3, o = c & 7;
    WhT[((size_t)(h * 16 + o)) * NN + (m0 + m)] = f2bf(s);
  }
  __syncthreads();
  if (t < 64) {
    int h = t >> 4, m = t & 15;
    float s1 = 0.f, s2 = 0.f;
#pragma unroll
    for (int o = 0; o < 8; ++o) {
      float v = whole[m][h * 8 + o];
      s1 += v * a[h * 16 + o];
      s2 += v * a[h * 16 + 8 + o];
    }
    ssrc[h * NN + m0 + m] = s1 * L2EF;     // pre-scaled by log2(e)
    sdst[h * NN + m0 + m] = s2 * L2EF;
    float mx = s2 * L2EF;
#pragma unroll
    for (int mm = 1; mm <= 8; mm <<= 1) mx = fmaxf(mx, __shfl_xor(mx, mm));
    if ((t & 15) == 0) atomicMax(&mhatU[h], fenc(mx));
  }
}

// ---------- kD: 256 blocks x 1024 thr. dbuf 256-j tiles, counted vmcnt(3) ----------
// wave w: head h=w&3, j-quarter jq=w>>2 (64 j/tile = 2 chunks of 32).
// Stage (3 gll per wave, uniform): 2x wh (4 WhT rows), + {w<4: sd | w=4,5: mask gll4
// | w>=6: dummy to scratch}. whS rows XOR-swizzled via pre-swizzled source.
__global__ __launch_bounds__(1024) void kD(const unsigned* __restrict__ maskW,
                                           const short* __restrict__ WhT,
                                           const float* __restrict__ ssrcg, const float* __restrict__ sdstg,
                                           const unsigned* __restrict__ mhatU,
                                           const float* __restrict__ wlin,
                                           float* __restrict__ outF, float* __restrict__ neF) {
  __shared__ short    whS[2][4][16][256];   // 2 x 32 KB  (row = (h*16+o), 512 B, swizzled)
  __shared__ float    sdS[2][4][256];       // 2 x 4 KB
  __shared__ unsigned adjBS[2][128];        // 2 x 512 B : [16 rows][8 words]
  __shared__ char     dummyS[1024];         // pad-DMA target (distinct dest, no CSE)
  __shared__ float    red[16][16][10];      // 10 KB
  __shared__ float    ps[2][8];
  int t = threadIdx.x;
  int w = t >> 6, lane = t & 63;
  int h = w & 3, jq = w >> 2;
  int m = lane & 15, q = lane >> 4;
  int i0 = blockIdx.x * 16;
  unsigned km = (unsigned)((m & 7) << 4);
  int r0 = 4 * w, laneHalf = lane >> 5, ln31 = lane & 31;

  float mh  = fdec(mhatU[h]);                // pre-scaled
  float ssr = ssrcg[h * NN + i0 + m];        // pre-scaled
  float tb  = ssr + mh;
  float eb  = fmaxf(tb, 0.2f * tb);
  f32x4 acc = {0.f, 0.f, 0.f, 0.f};

#define STAGE(BUF, JT)                                                              \
  { int rA = r0 + laneHalf;                                                         \
    const char* sA = (const char*)(WhT + (size_t)rA * NN + (JT) * 256)              \
                     + ((ln31 * 16) ^ ((rA & 7) << 4));                             \
    gll16(sA, (char*)whS + (BUF) * 32768 + r0 * 512);                               \
    int rB = r0 + 2 + laneHalf;                                                     \
    const char* sB = (const char*)(WhT + (size_t)rB * NN + (JT) * 256)              \
                     + ((ln31 * 16) ^ ((rB & 7) << 4));                             \
    gll16(sB, (char*)whS + (BUF) * 32768 + (r0 + 2) * 512);                         \
    if (w < 4) {                                                                    \
      const char* sS = (const char*)(sdstg + (size_t)w * NN + (JT) * 256) + lane * 16; \
      gll16(sS, (char*)sdS + (BUF) * 4096 + w * 1024);                              \
    } else if (w < 6) {                                                             \
      int k = w - 4;                                                                \
      const char* sM = (const char*)(maskW + (size_t)(i0 + k * 8 + (lane >> 3)) * 128 \
                                     + (JT) * 8 + (lane & 7));                      \
      gll4(sM, (char*)adjBS + (BUF) * 512 + k * 256);                               \
    } else {                                                                        \
      gll16(sA, dummyS);                                                            \
    }                                                                               \
  }

#define CHUNK(BUF, C)                                                               \
  { unsigned mword = adjBS[BUF][m * 8 + jq * 2 + (C)];                              \
    unsigned mbyte = (mword >> (q * 8)) & 255u;                                     \
    const char* sdB = (const char*)&sdS[BUF][h][0] + jq * 256 + (C) * 128 + q * 32; \
    f32x4 s0 = *(const f32x4*)sdB;                                                  \
    f32x4 s1 = *(const f32x4*)(sdB + 16);                                           \
    const char* whB = (const char*)&whS[BUF][h][m][0];                              \
    bf16x8 bv = *(const bf16x8*)(whB + (((unsigned)(jq * 128 + (C) * 64 + q * 16)) ^ km)); \
    bf16x8 af;                                                                      \
    _Pragma("unroll")                                                               \
    for (int e = 0; e < 4; ++e) {                                                   \
      float tt = ssr + s0[e];                                                       \
      float ee = fmaxf(tt, 0.2f * tt);                                              \
      float wv = __builtin_amdgcn_exp2f(ee - eb);                                   \
      af[e] = (mbyte & (1u << e)) ? f2bf(wv) : (short)0;                            \
    }                                                                               \
    _Pragma("unroll")                                                               \
    for (int e = 0; e < 4; ++e) {                                                   \
      float tt = ssr + s1[e];                                                       \
      float ee = fmaxf(tt, 0.2f * tt);                                              \
      float wv = __builtin_amdgcn_exp2f(ee - eb);                                   \
      af[4 + e] = (mbyte & (16u << e)) ? f2bf(wv) : (short)0;                       \
    }                                                                               \
    acc = __builtin_amdgcn_mfma_f32_16x16x32_bf16(af, bv, acc, 0, 0, 0);            \
  }

  asm volatile("s_waitcnt vmcnt(0)" ::: "memory");   // drain pre-loop scalar loads
  STAGE(0, 0)
#pragma unroll
  for (int jt = 0; jt < 16; ++jt) {
    const int buf = jt & 1;
    if (jt < 15) { STAGE(buf ^ 1, jt + 1) }
    if (jt < 15) { asm volatile("s_waitcnt vmcnt(3)" ::: "memory"); }
    else         { asm volatile("s_waitcnt vmcnt(0)" ::: "memory"); }
    __builtin_amdgcn_s_barrier();
    CHUNK(buf, 0)
    CHUNK(buf, 1)
    __builtin_amdgcn_s_barrier();
  }
#undef STAGE
#undef CHUNK

  __syncthreads();
  if (m < 9) {
#pragma unroll
    for (int r = 0; r < 4; ++r) red[w][q * 4 + r][m] = acc[r];
  }
  __syncthreads();
  if (t < 128) {
    int i = t >> 3, o = t & 7;
    float tot = 0.f;
#pragma unroll
    for (int hh = 0; hh < 4; ++hh) {
      float s = 0.f, l = 0.f;
#pragma unroll
      for (int jj = 0; jj < 4; ++jj) {
        int w2 = jj * 4 + hh;
        s += red[w2][i][o];
        l += red[w2][i][8];
      }
      tot += s / l;
    }
    float ne = 0.25f * tot;
    neF[(size_t)(i0 + i) * NC + o] = ne;
    float mx = ne;
#pragma unroll
    for (int mm = 1; mm <= 4; mm <<= 1) mx = fmaxf(mx, __shfl_xor(mx, mm));
    float ex = __expf(ne - mx);
    float s8 = ex;
#pragma unroll
    for (int mm = 1; mm <= 4; mm <<= 1) s8 += __shfl_xor(s8, mm);
    float ln = mx + __logf(s8);
    float p = (ne - ln) * wlin[i0 + i];
#pragma unroll
    for (int mm = 8; mm <= 32; mm <<= 1) p += __shfl_xor(p, mm);
    if ((t & 63) < 8) ps[t >> 6][t & 7] = p;
  }
  __syncthreads();
  if (t < 8) atomicAdd(&outF[t], ps[0][t] + ps[1][t]);
}

extern "C" void kernel_launch(void* const* d_in, const int* in_sizes, int n_in,
                              void* d_out, int out_size, void* d_ws, size_t ws_size,
                              hipStream_t stream) {
  const void* big0 = nullptr; const void* big1 = nullptr;
  const float* W = nullptr; const float* a = nullptr;
  const float* wlin = nullptr; const float* blin = nullptr;
  for (int idx = 0; idx < n_in; ++idx) {
    int sz = in_sizes[idx];
    if (sz == NN * NN)          { if (!big0) big0 = d_in[idx]; else big1 = d_in[idx]; }
    else if (sz == 4 * NN * NC) W    = (const float*)d_in[idx];
    else if (sz == 64)          a    = (const float*)d_in[idx];
    else if (sz == NN)          wlin = (const float*)d_in[idx];
    else if (sz == 1)           blin = (const float*)d_in[idx];
  }
  float* outF = (float*)d_out;       // fp32: [8] out | [4096][8] node_embeddings
  float* neF  = outF + 8;

  char* ws = (char*)d_ws;
  short*    Wt    = (short*)(ws + 0);         // 262144 B
  short*    WhT   = (short*)(ws + 262144);    // 524288 B : [4h*16][4096] bf16 (row h*16+8 = ones)
  float*    ssrc  = (float*)(ws + 786432);    // 65536 B (pre-scaled by log2 e)
  float*    sdst  = (float*)(ws + 851968);    // 65536 B (pre-scaled by log2 e)
  unsigned* mhatU = (unsigned*)(ws + 917504); // 16 B
  unsigned* maskW = (unsigned*)(ws + 1048576);// 2 MB : [4096 rows][128 words] adj bitmask

  kA0<<<2048, 256, 0, stream>>>(W, Wt, WhT, blin, outF, mhatU, big0, big1, maskW);
  kA <<<256, 1024, 0, stream>>>(big0, big1, Wt, WhT, ssrc, sdst, a, mhatU);
  kD <<<256, 1024, 0, stream>>>(maskW, WhT, ssrc, sdst, mhatU, wlin, outF, neF);
}